// Round 7
// baseline (297.890 us; speedup 1.0000x reference)
//
#include <hip/hip_runtime.h>

// ---------- types ----------
typedef float f32x4 __attribute__((ext_vector_type(4)));
typedef __bf16 bf16x8 __attribute__((ext_vector_type(8)));
typedef short short8 __attribute__((ext_vector_type(8)));

// ---------- bf16 helpers (RNE) ----------
__device__ __forceinline__ short f2bf(float f) {
    union { float f; unsigned u; } x; x.f = f;
    unsigned r = x.u + 0x7fffu + ((x.u >> 16) & 1u);
    return (short)(r >> 16);
}

__device__ __forceinline__ void store_out(float* p, float v) { *p = v; }
__device__ __forceinline__ void store_out(short* p, float v) { *p = f2bf(v); }

// async global->LDS, 16B per lane; lds dest = wave-uniform base (HW adds lane*16)
__device__ __forceinline__ void gload_lds16(const short* g, short* l) {
    __builtin_amdgcn_global_load_lds(
        (__attribute__((address_space(1))) void*)(void*)g,
        (__attribute__((address_space(3))) void*)l, 16, 0, 0);
}

// ---------- fused prep: x->bf16 cvt + all weight transposes, one dispatch ----------
// blocks: [0,8192) cvt x ; [8192,12288) Wq->WqkvT ; [12288,16384) Wo->WoT ;
// [16384,17408) Wk->WkT ; [17408,18432) Wv->WvT ; [18432,19456) Wkv->WqkvT+D*D
__global__ void prep_all(const float* __restrict__ x, short* __restrict__ xb,
                         const float* __restrict__ Wq, const float* __restrict__ Wo,
                         const float* __restrict__ Wk, const float* __restrict__ Wv,
                         const float* __restrict__ Wkv,
                         short* __restrict__ WqkvT, short* __restrict__ WoT,
                         short* __restrict__ WkT, short* __restrict__ WvT) {
    __shared__ float tile[32][33];
    int id = blockIdx.x;
    const int t = threadIdx.x;
    if (id < 8192) {
        const int i = id * 256 + t;
        float4 v = ((const float4*)x)[i];
        ((short4*)xb)[i] = make_short4(f2bf(v.x), f2bf(v.y), f2bf(v.z), f2bf(v.w));
        return;
    }
    id -= 8192;
    const float* in; short* out; int R, C, xt, yt;
    if (id < 4096)       { in = Wq;  out = WqkvT; R = 2048; C = 2048; xt = id & 63; yt = id >> 6; }
    else if (id < 8192)  { id -= 4096; in = Wo;  out = WoT;  R = 2048; C = 2048; xt = id & 63; yt = id >> 6; }
    else if (id < 9216)  { id -= 8192; in = Wk;  out = WkT;  R = 512;  C = 2048; xt = id & 63; yt = id >> 6; }
    else if (id < 10240) { id -= 9216; in = Wv;  out = WvT;  R = 512;  C = 2048; xt = id & 63; yt = id >> 6; }
    else                 { id -= 10240; in = Wkv; out = WqkvT + (size_t)2048 * 2048;
                           R = 2048; C = 512; xt = id & 15; yt = id >> 4; }
    const int c0 = xt * 32, r0 = yt * 32;
    const int tx = t & 31, ty = t >> 5;
#pragma unroll
    for (int i = 0; i < 32; i += 8)
        tile[ty + i][tx] = in[(size_t)(r0 + ty + i) * C + c0 + tx];
    __syncthreads();
#pragma unroll
    for (int i = 0; i < 32; i += 8)
        out[(size_t)(c0 + ty + i) * R + r0 + tx] = f2bf(tile[tx][ty + i]);
}

// ---------- bf16 GEMM core: C[M][N] = A[M][K]*Bt[N][K]^T, 128x128 tile ----------
// BK=64, XOR-swizzled LDS (row r: source chunk c at pos c^(r&7)), 16x16x32 MFMA.
// Zero bank conflicts (verified R4).
template <typename OutT>
__device__ __forceinline__ void gemm16_core(
    const short* __restrict__ A, const short* __restrict__ Bt, OutT* __restrict__ C,
    int m0, int n0, int K, int lda, int ldb, int ldc, short* sA, short* sB) {
    const int t = threadIdx.x;
    const int w = t >> 6, l = t & 63;
    const int wr = w >> 1, wc = w & 1;
    const int lg = l >> 4, ln = l & 15;

    f32x4 acc[4][4] = {};

    const int r_off = w * 32 + (l >> 3);
    const int c8 = (((l & 7) ^ (l >> 3)) & 7) * 8;
    const short* aB = A + (size_t)(m0 + r_off) * lda + c8;
    const short* bB = Bt + (size_t)(n0 + r_off) * ldb + c8;
    short* sAw = sA + w * 2048;
    short* sBw = sB + w * 2048;

    for (int kk = 0; kk < K; kk += 64) {
#pragma unroll
        for (int p = 0; p < 4; ++p) {
            gload_lds16(aB + kk + (size_t)(p * 8) * lda, sAw + p * 512);
            gload_lds16(bB + kk + (size_t)(p * 8) * ldb, sBw + p * 512);
        }
        __syncthreads();
#pragma unroll
        for (int ks = 0; ks < 2; ++ks) {
            const int pos = (((ks * 4 + lg) ^ (ln & 7)) & 7) * 8;
            bf16x8 af[4], bfr[4];
#pragma unroll
            for (int mi = 0; mi < 4; ++mi)
                af[mi] = *(const bf16x8*)&sA[(wr * 64 + mi * 16 + ln) * 64 + pos];
#pragma unroll
            for (int ni = 0; ni < 4; ++ni)
                bfr[ni] = *(const bf16x8*)&sB[(wc * 64 + ni * 16 + ln) * 64 + pos];
#pragma unroll
            for (int mi = 0; mi < 4; ++mi)
#pragma unroll
                for (int ni = 0; ni < 4; ++ni)
                    acc[mi][ni] = __builtin_amdgcn_mfma_f32_16x16x32_bf16(
                        af[mi], bfr[ni], acc[mi][ni], 0, 0, 0);
        }
        __syncthreads();
    }
#pragma unroll
    for (int mi = 0; mi < 4; ++mi) {
#pragma unroll
        for (int ni = 0; ni < 4; ++ni) {
            const int col = n0 + wc * 64 + ni * 16 + ln;
#pragma unroll
            for (int r = 0; r < 4; ++r) {
                const int row = m0 + wr * 64 + mi * 16 + lg * 4 + r;
                store_out(&C[(size_t)row * ldc + col], acc[mi][ni][r]);
            }
        }
    }
}

template <typename OutT>
__global__ __launch_bounds__(256, 2)
void gemm16(const short* __restrict__ A, const short* __restrict__ Bt,
            OutT* __restrict__ C, int K, int lda, int ldb, int ldc) {
    __shared__ __align__(16) short sA[128 * 64];
    __shared__ __align__(16) short sB[128 * 64];
    gemm16_core<OutT>(A, Bt, C, blockIdx.y * 128, blockIdx.x * 128, K, lda, ldb, ldc, sA, sB);
}

// fused kk + vT GEMMs (both read kvl, K=512), 1024 blocks
__global__ __launch_bounds__(256, 2)
void gemm16_kv(const short* __restrict__ kvl, const short* __restrict__ WkT,
               short* __restrict__ kk, const short* __restrict__ WvT,
               short* __restrict__ vT) {
    __shared__ __align__(16) short sA[128 * 64];
    __shared__ __align__(16) short sB[128 * 64];
    int id = blockIdx.x;
    if (id < 512) {
        // kk[4096][2048] = kvl[4096][512] * WkT[2048][512]^T
        gemm16_core<short>(kvl, WkT, kk, (id >> 4) * 128, (id & 15) * 128,
                           512, 2560, 512, 2048, sA, sB);
    } else {
        id -= 512;
        // vT[2048][4096] = WvT[2048][512] * kvl[4096][512]^T
        gemm16_core<short>(WvT, kvl, vT, (id >> 5) * 128, (id & 31) * 128,
                           512, 512, 2560, 4096, sA, sB);
    }
}

// ---------- attention: sliding window 128 + sink 16, causal ----------
// Barrier-free: K/V fragments loaded directly from global (both are 16B-contiguous
// per fragment), P via per-wave LDS (intra-wave lgkmcnt only). Each wave iterates
// only its own chunk list (1-6 chunks for its 16 queries).
#define A_S 2048
#define A_D 2048
#define A_M 4096
#define A_HD 128
__global__ __launch_bounds__(256)
void attn_win4(const short* __restrict__ Q, const short* __restrict__ K,
               const short* __restrict__ vT, short* __restrict__ O, int ldq) {
    const int qt = blockIdx.x, h = blockIdx.y, b = blockIdx.z;
    const int t = threadIdx.x, w = t >> 6, l = t & 63;
    const int qs = qt * 64 + w * 16;
    const int lg = l >> 4, ln = l & 15;
    const float SCALE = 0.088388347648318447f;  // 1/sqrt(128)

    __shared__ __align__(16) short sP[4][16][40];   // per-wave bf16 P, stride 40

    const size_t bS = (size_t)b * A_S;
    // Q A-fragments: row = qs + ln, k = ks*32 + lg*8 + j
    const short* qrow = Q + (bS + qs + ln) * ldq + h * A_HD;
    bf16x8 qf[4];
#pragma unroll
    for (int ks = 0; ks < 4; ++ks)
        qf[ks] = *(const bf16x8*)(qrow + ks * 32 + lg * 8);

    f32x4 o[8] = {};                  // C-layout: row q=lg*4+r, col d=dgi*16+ln
    float lsum[4] = {0.f, 0.f, 0.f, 0.f};

    // per-wave chunk list: sink chunk 0 (if disjoint) + window chunks [clo, chi]
    int clo = (qs - 127) >> 5; if (clo < 0) clo = 0;
    const int chi = (qs + 15) >> 5;
    const bool sink = clo > 0;
    const int nch = (chi - clo + 1) + (sink ? 1 : 0);

    const short* Kb = K + bS * A_D + h * A_HD;
    const short* Vb = vT + (size_t)h * A_HD * A_M + b * A_S;

    for (int ci = 0; ci < nch; ++ci) {
        const int kb = ((sink && ci == 0) ? 0 : (clo + ci - (sink ? 1 : 0))) * 32;
        // ---- QK^T: K B-fragments straight from global (16B contiguous/lane) ----
        const short* krow0 = Kb + (size_t)(kb + ln) * A_D + lg * 8;
        const short* krow1 = Kb + (size_t)(kb + 16 + ln) * A_D + lg * 8;
        f32x4 s0 = {0.f, 0.f, 0.f, 0.f}, s1 = {0.f, 0.f, 0.f, 0.f};
#pragma unroll
        for (int ks = 0; ks < 4; ++ks) {
            bf16x8 k0 = *(const bf16x8*)(krow0 + ks * 32);
            bf16x8 k1 = *(const bf16x8*)(krow1 + ks * 32);
            s0 = __builtin_amdgcn_mfma_f32_16x16x32_bf16(qf[ks], k0, s0, 0, 0, 0);
            s1 = __builtin_amdgcn_mfma_f32_16x16x32_bf16(qf[ks], k1, s1, 0, 0, 0);
        }
        // ---- masked exp (fixed m=0), per-lane partial row sums ----
        const int k0i = kb + ln, k1i = kb + 16 + ln;
#pragma unroll
        for (int r = 0; r < 4; ++r) {
            const int qi = qs + lg * 4 + r;
            const bool m0 = (k0i <= qi) && ((qi - k0i < 128) || (k0i < 16));
            const bool m1 = (k1i <= qi) && ((qi - k1i < 128) || (k1i < 16));
            const float p0 = m0 ? __expf(s0[r] * SCALE) : 0.f;
            const float p1 = m1 ? __expf(s1[r] * SCALE) : 0.f;
            lsum[r] += p0 + p1;
            sP[w][lg * 4 + r][ln] = f2bf(p0);
            sP[w][lg * 4 + r][16 + ln] = f2bf(p1);
        }
        // ---- P A-fragment: row q=ln, k=lg*8+j (intra-wave LDS round trip) ----
        bf16x8 pf = *(const bf16x8*)&sP[w][ln][lg * 8];
        // ---- PV: V B-fragments straight from global vT (16B contiguous/lane) ----
        const short* vcol = Vb + kb + lg * 8;
#pragma unroll
        for (int dgi = 0; dgi < 8; ++dgi) {
            bf16x8 vf = *(const bf16x8*)(vcol + (size_t)(dgi * 16 + ln) * A_M);
            o[dgi] = __builtin_amdgcn_mfma_f32_16x16x32_bf16(pf, vf, o[dgi], 0, 0, 0);
        }
    }

    // ---- final row-sum reduction + normalize + store ----
#pragma unroll
    for (int r = 0; r < 4; ++r) {
        float s = lsum[r];
        s += __shfl_xor(s, 1); s += __shfl_xor(s, 2);
        s += __shfl_xor(s, 4); s += __shfl_xor(s, 8);
        const float inv = 1.0f / s;
        short* orow = O + (bS + qs + lg * 4 + r) * A_D + h * A_HD + ln;
#pragma unroll
        for (int dgi = 0; dgi < 8; ++dgi)
            orow[dgi * 16] = f2bf(o[dgi][r] * inv);
    }
}

// ---------- host ----------
extern "C" void kernel_launch(void* const* d_in, const int* in_sizes, int n_in,
                              void* d_out, int out_size, void* d_ws, size_t ws_size,
                              hipStream_t stream) {
    (void)in_sizes; (void)n_in; (void)out_size; (void)ws_size;
    const float* x   = (const float*)d_in[0];
    const float* Wq  = (const float*)d_in[1];
    const float* Wkv = (const float*)d_in[2];
    const float* Wk  = (const float*)d_in[3];
    const float* Wv  = (const float*)d_in[4];
    const float* Wo  = (const float*)d_in[5];
    float* out = (float*)d_out;

    const int B = 2, S = 2048, D = 2048, L = 512, H = 16;
    const int M = B * S;       // 4096
    const int NQ = D + L;      // 2560 (fused q|kvl)

    short* p = (short*)d_ws;
    short* xb    = p; p += (size_t)M * D;
    short* WqkvT = p; p += (size_t)NQ * D;
    short* WkT   = p; p += (size_t)D * L;
    short* WvT   = p; p += (size_t)D * L;
    short* WoT   = p; p += (size_t)D * D;
    short* qkv   = p; p += (size_t)M * NQ;
    short* kk    = p; p += (size_t)M * D;
    short* vT    = p; p += (size_t)D * M;
    short* ao    = p; p += (size_t)M * D;

    prep_all<<<19456, 256, 0, stream>>>(x, xb, Wq, Wo, Wk, Wv, Wkv,
                                        WqkvT, WoT, WkT, WvT);
    gemm16<short><<<dim3(NQ / 128, M / 128), 256, 0, stream>>>(
        xb, WqkvT, qkv, D, D, D, NQ);
    gemm16_kv<<<1024, 256, 0, stream>>>(qkv + D, WkT, kk, WvT, vT);

    attn_win4<<<dim3(S / 64, H, B), 256, 0, stream>>>(qkv, kk, vT, ao, NQ);

    gemm16<float><<<dim3(D / 128, M / 128), 256, 0, stream>>>(
        ao, WoT, out, D, D, D, D);
}